// Round 10
// baseline (247.097 us; speedup 1.0000x reference)
//
#include <hip/hip_runtime.h>

// CubeLens: radial lens deflection + bilinear gather + 4x4 avg pool.
// C=64, NS=256, NL=192, UPS=4. Output (64,192,192) fp32.
//
// R10: R9's fusion with a MANUAL device-scope barrier instead of
// hipLaunchCooperativeKernel (which failed silently -> zero output).
//   grid = 1024 = 256 CU x 4 blocks; __launch_bounds__(256,4) + 18.9KB LDS
//   guarantee co-residency. Counter in d_ws (zeroed via hipMemsetAsync each
//   call). Release: __threadfence + agent-scope fetch_add; acquire:
//   agent-scope spin load + __threadfence. clock64 timeout = no-hang escape.
//   Phase A: fp32->fp16 channel-last transpose, XCD-swizzled tile order
//            (each XCD's L2 keeps the band it wrote).
//   Phase B: R8 gather (tap table in LDS, batched f16x8 corner loads,
//            mode gating, LDS repack, nontemporal stores), grid-stride
//            1152 tiles, XCD-swizzled.

#define NSRC 256
#define NLENS 192
#define NPIX (NLENS * NLENS)     // 36864
#define CSZ  64
#define PXB  32                  // pixels per gather tile
#define NBLK (NPIX / PXB)        // 1152 gather tiles, divisible by 8
#define GRID 1024                // 256 CUs x 4 blocks/CU, co-resident
#define NTTILE (NSRC * NSRC / 64)  // 1024 transpose tiles

typedef float    f32x4 __attribute__((ext_vector_type(4)));
typedef _Float16 f16x8 __attribute__((ext_vector_type(8)));

// ---------------- fallback (round-1 kernel, used only if ws too small) ------
__global__ __launch_bounds__(256) void cubelens_fallback(
    const float* __restrict__ src, const float* __restrict__ theta_p,
    float* __restrict__ out)
{
    const float tE = theta_p[0];
    const int pix = blockIdx.x * 256 + threadIdx.x;
    const int c0  = blockIdx.y * 8;
    const int lx  = pix % NLENS;
    const int ly  = pix / NLENS;
    float acc[8];
#pragma unroll
    for (int c = 0; c < 8; ++c) acc[c] = 0.0f;
    const float* __restrict__ srcg = src + (size_t)c0 * (NSRC * NSRC);
#pragma unroll
    for (int uy = 0; uy < 4; ++uy) {
        const float thy = ((float)(ly * 4 + uy) - 383.5f) * 0.01f;
#pragma unroll
        for (int ux = 0; ux < 4; ++ux) {
            const float thx = ((float)(lx * 4 + ux) - 383.5f) * 0.01f;
            const float r  = sqrtf(thx * thx + thy * thy) + 1e-8f;
            const float fx = (thx - (tE * thx) / r) / 0.02f + 127.5f;
            const float fy = (thy - (tE * thy) / r) / 0.02f + 127.5f;
            const bool inb = (fx >= 0.0f) & (fx <= 255.0f) &
                             (fy >= 0.0f) & (fy <= 255.0f);
            if (!inb) continue;
            int x0 = min(max((int)floorf(fx), 0), 254);
            int y0 = min(max((int)floorf(fy), 0), 254);
            const float wx = fminf(fmaxf(fx - (float)x0, 0.0f), 1.0f);
            const float wy = fminf(fmaxf(fy - (float)y0, 0.0f), 1.0f);
            const float w00 = (1.0f - wy) * (1.0f - wx);
            const float w01 = (1.0f - wy) * wx;
            const float w10 = wy * (1.0f - wx);
            const float w11 = wy * wx;
            const float* __restrict__ p = srcg + y0 * NSRC + x0;
#pragma unroll
            for (int c = 0; c < 8; ++c) {
                const float* __restrict__ pc = p + c * (NSRC * NSRC);
                acc[c] += w00 * pc[0] + w01 * pc[1]
                        + w10 * pc[NSRC] + w11 * pc[NSRC + 1];
            }
        }
    }
#pragma unroll
    for (int c = 0; c < 8; ++c)
        out[(size_t)(c0 + c) * NPIX + pix] = acc[c] * 0.0625f;
}

// ---------------- fused kernel ----------------------------------------------
struct Tap { int x0, y0; float wx, wy; bool inb; };

__device__ __forceinline__ Tap tapgeom(int p, int sub, float tE) {
    const int lx = p % NLENS, ly = p / NLENS;
    const float thy = ((float)(ly * 4 + (sub >> 2)) - 383.5f) * 0.01f;
    const float thx = ((float)(lx * 4 + (sub & 3))  - 383.5f) * 0.01f;
    const float r  = sqrtf(thx * thx + thy * thy) + 1e-8f;
    const float fx = (thx - (tE * thx) / r) / 0.02f + 127.5f;
    const float fy = (thy - (tE * thy) / r) / 0.02f + 127.5f;
    Tap tp;
    tp.inb = (fx >= 0.0f) & (fx <= 255.0f) & (fy >= 0.0f) & (fy <= 255.0f);
    tp.x0 = min(max((int)floorf(fx), 0), 254);
    tp.y0 = min(max((int)floorf(fy), 0), 254);
    tp.wx = fminf(fmaxf(fx - (float)tp.x0, 0.0f), 1.0f);
    tp.wy = fminf(fmaxf(fy - (float)tp.y0, 0.0f), 1.0f);
    return tp;
}

struct SmemT { float tile[CSZ][65]; };                    // 16.6 KB
struct SmemG {                                            // 18.9 KB
    f32x4 Btap[PXB][16];
    float wpatch[PXB][16];
    int   gbase[PXB];
    int   gmode[PXB];
    float smemO[CSZ][PXB + 1];
};

__global__ __launch_bounds__(256, 4) void cubelens_fused(
    const float* __restrict__ src,      // (64,256,256) fp32
    const float* __restrict__ theta_p,
    float* __restrict__ out,            // (64,192,192) fp32
    _Float16* __restrict__ ws,          // (256,256,64) fp16
    unsigned int* __restrict__ cnt)     // barrier counter (zeroed per call)
{
    __shared__ union { SmemT tr; SmemG g; } sm;
    const float tE = theta_p[0];
    const int t = threadIdx.x;
    const int bid = blockIdx.x;

    // ---- Phase A: transpose one 64-px tile (XCD-swizzled tile order) ----
    {
        const int tile = (bid & 7) * (NTTILE / 8) + (bid >> 3);
        const int p0 = tile * 64;
        {
            const int crow = t >> 4;            // 0..15
            const int px4  = (t & 15) * 4;      // 0..60
#pragma unroll
            for (int i = 0; i < 4; ++i) {
                const int c = crow + 16 * i;
                const f32x4 v = __builtin_nontemporal_load(
                    (const f32x4*)(src + (size_t)c * (NSRC * NSRC) + p0 + px4));
                sm.tr.tile[c][px4 + 0] = v.x; sm.tr.tile[c][px4 + 1] = v.y;
                sm.tr.tile[c][px4 + 2] = v.z; sm.tr.tile[c][px4 + 3] = v.w;
            }
        }
        __syncthreads();
        {
            const int c8 = (t & 7) * 8;
            const int pr = t >> 3;              // 0..31
#pragma unroll
            for (int i = 0; i < 2; ++i) {
                const int p = pr + 32 * i;
                f16x8 h;
#pragma unroll
                for (int k = 0; k < 8; ++k) h[k] = (_Float16)sm.tr.tile[c8 + k][p];
                *(f16x8*)(ws + (size_t)(p0 + p) * CSZ + c8) = h;
            }
        }
    }

    // ---- manual grid barrier (device scope, co-resident grid) ----
    __threadfence();              // release: ws writes visible device-wide
    __syncthreads();
    if (t == 0) {
        __hip_atomic_fetch_add(cnt, 1u, __ATOMIC_ACQ_REL,
                               __HIP_MEMORY_SCOPE_AGENT);
        const long long tstart = clock64();
        while (__hip_atomic_load(cnt, __ATOMIC_ACQUIRE,
                                 __HIP_MEMORY_SCOPE_AGENT) < GRID) {
            __builtin_amdgcn_s_sleep(2);
            if (clock64() - tstart > 50000000LL) break;   // no-hang escape
        }
    }
    __syncthreads();
    __threadfence();              // acquire: drop stale cached ws lines

    // ---- Phase B: gather, grid-stride over 1152 32-px tiles ----
    for (int gt = bid; gt < NBLK; gt += GRID) {
        const int pixblock = (gt & 7) * (NBLK / 8) + (gt >> 3);   // XCD swizzle
        const int p0 = pixblock * PXB;

        // 1A: tap geometry + patch base; lanes = (2px group, tap)
        {
            const int g = t >> 4, sub = t & 15;
#pragma unroll
            for (int h = 0; h < 2; ++h) {
                const int pi = 2 * g + h;
                const Tap tp = tapgeom(p0 + pi, sub, tE);
                const float x0f = (float)tp.x0, y0f = (float)tp.y0;
                float mnx = tp.inb ? x0f : 1e9f;
                float mny = tp.inb ? y0f : 1e9f;
#pragma unroll
                for (int off = 1; off < 16; off <<= 1) {
                    mnx = fminf(mnx, __shfl_xor(mnx, off, 16));
                    mny = fminf(mny, __shfl_xor(mny, off, 16));
                }
                const bool allout = (mnx > 5e8f);
                int viol = (tp.inb & ((x0f > mnx + 2.0f) | (y0f > mny + 2.0f))) ? 1 : 0;
#pragma unroll
                for (int off = 1; off < 16; off <<= 1)
                    viol |= __shfl_xor(viol, off, 16);
                const float bxc = fminf(mnx, 252.0f);
                const float byc = fminf(mny, 252.0f);
                f32x4 rec;
                rec.x = tp.inb ? (x0f - bxc) : -1000.0f;
                rec.y = tp.inb ? (y0f - byc) : -1000.0f;
                rec.z = tp.wx;
                rec.w = tp.wy;
                sm.g.Btap[pi][sub] = rec;
                if (sub == 0) {
                    sm.g.gbase[pi] = (((int)byc) * NSRC + (int)bxc) * CSZ;
                    sm.g.gmode[pi] = allout ? 0 : (viol ? 2 : 1);
                }
            }
        }
        __syncthreads();

        // 1B: corner weights; lanes = (pixel, corner); 2 px per lane
        {
            const int sub = t & 15;
            const float cxf = (float)(sub & 3), cyf = (float)(sub >> 2);
#pragma unroll
            for (int h = 0; h < 2; ++h) {
                const int pi = (t >> 4) + 16 * h;
                float myw = 0.0f;
#pragma unroll
                for (int j = 0; j < 16; ++j) {
                    const f32x4 r = sm.g.Btap[pi][j];
                    const float tx = cxf - r.x;
                    const float ty = cyf - r.y;
                    const float wxp = (tx == 0.0f) ? (1.0f - r.z)
                                    : ((tx == 1.0f) ? r.z : 0.0f);
                    const float wyp = (ty == 0.0f) ? (1.0f - r.w)
                                    : ((ty == 1.0f) ? r.w : 0.0f);
                    myw += wxp * wyp;
                }
                sm.g.wpatch[pi][sub] = myw * 0.0625f;
            }
        }
        __syncthreads();

        // 2: gather. thread = (pixel, 8-channel group)
        {
            const int pi = t >> 3, c8 = t & 7;
            const int mode = sm.g.gmode[pi];
            float acc[8];
#pragma unroll
            for (int e = 0; e < 8; ++e) acc[e] = 0.0f;

            if (mode == 1) {
                const _Float16* __restrict__ base = ws + sm.g.gbase[pi] + c8 * 8;
#pragma unroll
                for (int half = 0; half < 2; ++half) {
                    f16x8 v[8];
                    float w[8];
#pragma unroll
                    for (int k = 0; k < 8; ++k) {
                        const int cn = half * 8 + k;
                        v[k] = *(const f16x8*)(base + ((cn >> 2) * NSRC + (cn & 3)) * CSZ);
                        w[k] = sm.g.wpatch[pi][cn];
                    }
#pragma unroll
                    for (int k = 0; k < 8; ++k)
#pragma unroll
                        for (int e = 0; e < 8; ++e)
                            acc[e] += w[k] * (float)v[k][e];
                }
            } else if (mode == 2) {
                for (int tap = 0; tap < 16; ++tap) {
                    const Tap tp = tapgeom(p0 + pi, tap, tE);
                    if (tp.inb) {
                        const _Float16* __restrict__ pp =
                            ws + (tp.y0 * NSRC + tp.x0) * CSZ + c8 * 8;
                        const f16x8 v00 = *(const f16x8*)(pp);
                        const f16x8 v01 = *(const f16x8*)(pp + CSZ);
                        const f16x8 v10 = *(const f16x8*)(pp + NSRC * CSZ);
                        const f16x8 v11 = *(const f16x8*)(pp + NSRC * CSZ + CSZ);
                        const float w00 = (1.0f - tp.wy) * (1.0f - tp.wx);
                        const float w01 = (1.0f - tp.wy) * tp.wx;
                        const float w10 = tp.wy * (1.0f - tp.wx);
                        const float w11 = tp.wy * tp.wx;
#pragma unroll
                        for (int e = 0; e < 8; ++e)
                            acc[e] += w00 * (float)v00[e] + w01 * (float)v01[e]
                                    + w10 * (float)v10[e] + w11 * (float)v11[e];
                    }
                }
#pragma unroll
                for (int e = 0; e < 8; ++e) acc[e] *= 0.0625f;
            }

#pragma unroll
            for (int e = 0; e < 8; ++e) sm.g.smemO[c8 * 8 + e][pi] = acc[e];
        }
        __syncthreads();

        // epilogue: coalesced nontemporal f32x4 stores
        {
            const int c   = t >> 2;          // 0..63
            const int px8 = (t & 3) * 8;     // 0,8,16,24
            float* op = out + (size_t)c * NPIX + p0 + px8;
            f32x4 v0, v1;
            v0.x = sm.g.smemO[c][px8 + 0]; v0.y = sm.g.smemO[c][px8 + 1];
            v0.z = sm.g.smemO[c][px8 + 2]; v0.w = sm.g.smemO[c][px8 + 3];
            v1.x = sm.g.smemO[c][px8 + 4]; v1.y = sm.g.smemO[c][px8 + 5];
            v1.z = sm.g.smemO[c][px8 + 6]; v1.w = sm.g.smemO[c][px8 + 7];
            __builtin_nontemporal_store(v0, (f32x4*)op);
            __builtin_nontemporal_store(v1, (f32x4*)(op + 4));
        }
        __syncthreads();   // LDS reuse safety for next grid-stride tile
    }
}

extern "C" void kernel_launch(void* const* d_in, const int* in_sizes, int n_in,
                              void* d_out, int out_size, void* d_ws, size_t ws_size,
                              hipStream_t stream) {
    const float* src   = (const float*)d_in[0];
    const float* theta = (const float*)d_in[1];
    float* out = (float*)d_out;

    const size_t ws_bytes = (size_t)NSRC * NSRC * CSZ * sizeof(_Float16);  // 8.39 MB
    if (ws_size >= ws_bytes + 64) {
        _Float16* ws = (_Float16*)d_ws;
        unsigned int* cnt = (unsigned int*)((char*)d_ws + ws_bytes);
        hipMemsetAsync((void*)cnt, 0, sizeof(unsigned int), stream);
        cubelens_fused<<<dim3(GRID), dim3(256), 0, stream>>>(src, theta, out, ws, cnt);
    } else {
        cubelens_fallback<<<dim3(NPIX / 256, 8), dim3(256), 0, stream>>>(src, theta, out);
    }
}

// Round 11
// 29.782 us; speedup vs baseline: 8.2968x; 8.2968x over previous
//
#include <hip/hip_runtime.h>

// CubeLens: radial lens deflection + bilinear gather + 4x4 avg pool.
// C=64, NS=256, NL=192, UPS=4. Output (64,192,192) fp32.
//
// R11 = R8 two-kernel structure + T14 async-split in the main kernel:
//   k1: fp32->fp16 channel-last transpose, XCD-swizzled tile order
//       (writer XCD band ~= reader XCD band -> partial L2 locality).
//   k2: Phase 1A lane=(2px,tap): geometry, min/viol butterflies, tap
//         records -> LDS; gbase/gmode.
//       Phase 1B lane=(px,c8): ISSUE all 16 f16x8 corner loads for the
//         phase-2 pixel FIRST (T14 issue-early), then compute corner
//         weights (lane=(px,corner), 2px/lane) while loads fly.
//       Phase 2: pure FMA on landed loads + wpatch; mode-2 fallback.
//       Epilogue: LDS repack -> nontemporal f32x4 stores.

#define NSRC 256
#define NLENS 192
#define NPIX (NLENS * NLENS)     // 36864
#define CSZ  64
#define PXB  32                  // pixels per gather tile
#define NBLK (NPIX / PXB)        // 1152, divisible by 8
#define NTTILE (NSRC * NSRC / 64)  // 1024 transpose tiles

typedef float    f32x4 __attribute__((ext_vector_type(4)));
typedef _Float16 f16x8 __attribute__((ext_vector_type(8)));

// ---------------- fallback (round-1 kernel, used only if ws too small) ------
__global__ __launch_bounds__(256) void cubelens_fallback(
    const float* __restrict__ src, const float* __restrict__ theta_p,
    float* __restrict__ out)
{
    const float tE = theta_p[0];
    const int pix = blockIdx.x * 256 + threadIdx.x;
    const int c0  = blockIdx.y * 8;
    const int lx  = pix % NLENS;
    const int ly  = pix / NLENS;
    float acc[8];
#pragma unroll
    for (int c = 0; c < 8; ++c) acc[c] = 0.0f;
    const float* __restrict__ srcg = src + (size_t)c0 * (NSRC * NSRC);
#pragma unroll
    for (int uy = 0; uy < 4; ++uy) {
        const float thy = ((float)(ly * 4 + uy) - 383.5f) * 0.01f;
#pragma unroll
        for (int ux = 0; ux < 4; ++ux) {
            const float thx = ((float)(lx * 4 + ux) - 383.5f) * 0.01f;
            const float r  = sqrtf(thx * thx + thy * thy) + 1e-8f;
            const float fx = (thx - (tE * thx) / r) / 0.02f + 127.5f;
            const float fy = (thy - (tE * thy) / r) / 0.02f + 127.5f;
            const bool inb = (fx >= 0.0f) & (fx <= 255.0f) &
                             (fy >= 0.0f) & (fy <= 255.0f);
            if (!inb) continue;
            int x0 = min(max((int)floorf(fx), 0), 254);
            int y0 = min(max((int)floorf(fy), 0), 254);
            const float wx = fminf(fmaxf(fx - (float)x0, 0.0f), 1.0f);
            const float wy = fminf(fmaxf(fy - (float)y0, 0.0f), 1.0f);
            const float w00 = (1.0f - wy) * (1.0f - wx);
            const float w01 = (1.0f - wy) * wx;
            const float w10 = wy * (1.0f - wx);
            const float w11 = wy * wx;
            const float* __restrict__ p = srcg + y0 * NSRC + x0;
#pragma unroll
            for (int c = 0; c < 8; ++c) {
                const float* __restrict__ pc = p + c * (NSRC * NSRC);
                acc[c] += w00 * pc[0] + w01 * pc[1]
                        + w10 * pc[NSRC] + w11 * pc[NSRC + 1];
            }
        }
    }
#pragma unroll
    for (int c = 0; c < 8; ++c)
        out[(size_t)(c0 + c) * NPIX + pix] = acc[c] * 0.0625f;
}

// ---------------- k1: transpose (c,p) fp32 -> (p,c) fp16, XCD swizzle -------
__global__ __launch_bounds__(256) void transpose_kernel(
    const float* __restrict__ src, _Float16* __restrict__ ws)
{
    __shared__ float tile[CSZ][65];
    const int b = blockIdx.x;
    const int tileid = (b & 7) * (NTTILE / 8) + (b >> 3);   // XCD swizzle
    const int p0 = tileid * 64;
    const int t  = threadIdx.x;
    {
        const int crow = t >> 4;            // 0..15
        const int px4  = (t & 15) * 4;      // 0..60
#pragma unroll
        for (int i = 0; i < 4; ++i) {
            const int c = crow + 16 * i;
            const f32x4 v = __builtin_nontemporal_load(
                (const f32x4*)(src + (size_t)c * (NSRC * NSRC) + p0 + px4));
            tile[c][px4 + 0] = v.x; tile[c][px4 + 1] = v.y;
            tile[c][px4 + 2] = v.z; tile[c][px4 + 3] = v.w;
        }
    }
    __syncthreads();
    {
        const int c8 = (t & 7) * 8;
        const int pr = t >> 3;              // 0..31
#pragma unroll
        for (int i = 0; i < 2; ++i) {
            const int p = pr + 32 * i;
            f16x8 h;
#pragma unroll
            for (int k = 0; k < 8; ++k) h[k] = (_Float16)tile[c8 + k][p];
            *(f16x8*)(ws + (size_t)(p0 + p) * CSZ + c8) = h;
        }
    }
}

// ---------------- k2: lens gather ------------------------------------------
struct Tap { int x0, y0; float wx, wy; bool inb; };

__device__ __forceinline__ Tap tapgeom(int p, int sub, float tE) {
    const int lx = p % NLENS, ly = p / NLENS;
    const float thy = ((float)(ly * 4 + (sub >> 2)) - 383.5f) * 0.01f;
    const float thx = ((float)(lx * 4 + (sub & 3))  - 383.5f) * 0.01f;
    const float r  = sqrtf(thx * thx + thy * thy) + 1e-8f;
    const float fx = (thx - (tE * thx) / r) / 0.02f + 127.5f;
    const float fy = (thy - (tE * thy) / r) / 0.02f + 127.5f;
    Tap tp;
    tp.inb = (fx >= 0.0f) & (fx <= 255.0f) & (fy >= 0.0f) & (fy <= 255.0f);
    tp.x0 = min(max((int)floorf(fx), 0), 254);
    tp.y0 = min(max((int)floorf(fy), 0), 254);
    tp.wx = fminf(fmaxf(fx - (float)tp.x0, 0.0f), 1.0f);
    tp.wy = fminf(fmaxf(fy - (float)tp.y0, 0.0f), 1.0f);
    return tp;
}

__global__ __launch_bounds__(256) void cubelens_main(
    const _Float16* __restrict__ ws,    // (256,256,64) fp16
    const float* __restrict__ theta_p,
    float* __restrict__ out)            // (64,192,192) fp32
{
    __shared__ f32x4 Btap[PXB][16];     // per-tap {dx, dy, wx, wy}
    __shared__ float wpatch[PXB][16];   // per-pixel corner weights (pre /16)
    __shared__ int   gbase[PXB];
    __shared__ int   gmode[PXB];        // 0=skip 1=patch 2=fallback
    __shared__ float smemO[CSZ][PXB + 1];

    const float tE = theta_p[0];
    const int b = blockIdx.x;
    const int pixblock = (b & 7) * (NBLK / 8) + (b >> 3);   // XCD swizzle
    const int p0 = pixblock * PXB;
    const int t  = threadIdx.x;

    // ---- phase 1A: tap geometry + patch base; lanes = (2px group, tap) ----
    {
        const int g = t >> 4, sub = t & 15;
#pragma unroll
        for (int h = 0; h < 2; ++h) {
            const int pi = 2 * g + h;
            const Tap tp = tapgeom(p0 + pi, sub, tE);
            const float x0f = (float)tp.x0, y0f = (float)tp.y0;
            float mnx = tp.inb ? x0f : 1e9f;
            float mny = tp.inb ? y0f : 1e9f;
#pragma unroll
            for (int off = 1; off < 16; off <<= 1) {
                mnx = fminf(mnx, __shfl_xor(mnx, off, 16));
                mny = fminf(mny, __shfl_xor(mny, off, 16));
            }
            const bool allout = (mnx > 5e8f);
            int viol = (tp.inb & ((x0f > mnx + 2.0f) | (y0f > mny + 2.0f))) ? 1 : 0;
#pragma unroll
            for (int off = 1; off < 16; off <<= 1)
                viol |= __shfl_xor(viol, off, 16);
            const float bxc = fminf(mnx, 252.0f);
            const float byc = fminf(mny, 252.0f);
            f32x4 rec;
            rec.x = tp.inb ? (x0f - bxc) : -1000.0f;
            rec.y = tp.inb ? (y0f - byc) : -1000.0f;
            rec.z = tp.wx;
            rec.w = tp.wy;
            Btap[pi][sub] = rec;
            if (sub == 0) {
                gbase[pi] = (((int)byc) * NSRC + (int)bxc) * CSZ;
                gmode[pi] = allout ? 0 : (viol ? 2 : 1);
            }
        }
    }
    __syncthreads();

    // ---- phase 1B: T14 issue-early loads, then weights while in flight ----
    const int pi2 = t >> 3, c8 = t & 7;       // this thread's phase-2 pixel
    const int mode2 = gmode[pi2];
    f16x8 v[16];
    if (mode2 == 1) {
        const _Float16* __restrict__ base = ws + gbase[pi2] + c8 * 8;
#pragma unroll
        for (int cn = 0; cn < 16; ++cn)
            v[cn] = *(const f16x8*)(base + ((cn >> 2) * NSRC + (cn & 3)) * CSZ);
    }
    // corner weights; lanes = (pixel, corner); 2 px per lane
    {
        const int sub = t & 15;
        const float cxf = (float)(sub & 3), cyf = (float)(sub >> 2);
#pragma unroll
        for (int h = 0; h < 2; ++h) {
            const int pi = (t >> 4) + 16 * h;
            float myw = 0.0f;
#pragma unroll
            for (int j = 0; j < 16; ++j) {
                const f32x4 r = Btap[pi][j];
                const float tx = cxf - r.x;
                const float ty = cyf - r.y;
                const float wxp = (tx == 0.0f) ? (1.0f - r.z)
                                : ((tx == 1.0f) ? r.z : 0.0f);
                const float wyp = (ty == 0.0f) ? (1.0f - r.w)
                                : ((ty == 1.0f) ? r.w : 0.0f);
                myw += wxp * wyp;
            }
            wpatch[pi][sub] = myw * 0.0625f;
        }
    }
    __syncthreads();

    // ---- phase 2: pure FMA on landed loads ----
    {
        float acc[8];
#pragma unroll
        for (int e = 0; e < 8; ++e) acc[e] = 0.0f;

        if (mode2 == 1) {
#pragma unroll
            for (int cn = 0; cn < 16; ++cn) {
                const float w = wpatch[pi2][cn];
#pragma unroll
                for (int e = 0; e < 8; ++e)
                    acc[e] += w * (float)v[cn][e];     // v_fma_mix_f32
            }
        } else if (mode2 == 2) {
            for (int tap = 0; tap < 16; ++tap) {
                const Tap tp = tapgeom(p0 + pi2, tap, tE);
                if (tp.inb) {
                    const _Float16* __restrict__ pp =
                        ws + (tp.y0 * NSRC + tp.x0) * CSZ + c8 * 8;
                    const f16x8 v00 = *(const f16x8*)(pp);
                    const f16x8 v01 = *(const f16x8*)(pp + CSZ);
                    const f16x8 v10 = *(const f16x8*)(pp + NSRC * CSZ);
                    const f16x8 v11 = *(const f16x8*)(pp + NSRC * CSZ + CSZ);
                    const float w00 = (1.0f - tp.wy) * (1.0f - tp.wx);
                    const float w01 = (1.0f - tp.wy) * tp.wx;
                    const float w10 = tp.wy * (1.0f - tp.wx);
                    const float w11 = tp.wy * tp.wx;
#pragma unroll
                    for (int e = 0; e < 8; ++e)
                        acc[e] += w00 * (float)v00[e] + w01 * (float)v01[e]
                                + w10 * (float)v10[e] + w11 * (float)v11[e];
                }
            }
#pragma unroll
            for (int e = 0; e < 8; ++e) acc[e] *= 0.0625f;
        }

#pragma unroll
        for (int e = 0; e < 8; ++e) smemO[c8 * 8 + e][pi2] = acc[e];
    }
    __syncthreads();

    // ---- epilogue: coalesced nontemporal f32x4 stores ----
    {
        const int c   = t >> 2;          // 0..63
        const int px8 = (t & 3) * 8;     // 0,8,16,24
        float* op = out + (size_t)c * NPIX + p0 + px8;
        f32x4 v0, v1;
        v0.x = smemO[c][px8 + 0]; v0.y = smemO[c][px8 + 1];
        v0.z = smemO[c][px8 + 2]; v0.w = smemO[c][px8 + 3];
        v1.x = smemO[c][px8 + 4]; v1.y = smemO[c][px8 + 5];
        v1.z = smemO[c][px8 + 6]; v1.w = smemO[c][px8 + 7];
        __builtin_nontemporal_store(v0, (f32x4*)op);
        __builtin_nontemporal_store(v1, (f32x4*)(op + 4));
    }
}

extern "C" void kernel_launch(void* const* d_in, const int* in_sizes, int n_in,
                              void* d_out, int out_size, void* d_ws, size_t ws_size,
                              hipStream_t stream) {
    const float* src   = (const float*)d_in[0];
    const float* theta = (const float*)d_in[1];
    float* out = (float*)d_out;

    const size_t need = (size_t)CSZ * NSRC * NSRC * sizeof(_Float16);  // 8.4 MB
    if (ws_size >= need) {
        _Float16* ws = (_Float16*)d_ws;
        transpose_kernel<<<dim3(NTTILE), dim3(256), 0, stream>>>(src, ws);
        cubelens_main<<<dim3(NBLK), dim3(256), 0, stream>>>(ws, theta, out);
    } else {
        cubelens_fallback<<<dim3(NPIX / 256, 8), dim3(256), 0, stream>>>(src, theta, out);
    }
}